// Round 4
// baseline (5220.122 us; speedup 1.0000x reference)
//
#include <hip/hip_runtime.h>
#include <math.h>

#define HH 256
#define FIN 6
#define TT 4096
#define BB 32
#define TH 0.05f

typedef _Float16 h2 __attribute__((ext_vector_type(2)));
typedef int iv64 __attribute__((ext_vector_type(64)));   // 64 VGPRs, holds 64 packed h2
struct H8 { h2 a, b, c, d; };   // 16 B = 8 halfs

__device__ __forceinline__ int packh2(float a, float b) {
    h2 v = { (_Float16)a, (_Float16)b };
    return __builtin_bit_cast(int, v);
}
__device__ __forceinline__ h2 toh2(int x) { return __builtin_bit_cast(h2, x); }

__device__ __forceinline__ float hswish(float v) {
    float c = fminf(fmaxf(v + 3.0f, 0.0f), 6.0f);
    return v * c * (1.0f / 6.0f);
}
__device__ __forceinline__ float fexp2(float x) { return __builtin_amdgcn_exp2f(x); }
__device__ __forceinline__ float frcp(float x)  { return __builtin_amdgcn_rcpf(x); }
__device__ __forceinline__ float sigm(float x)  { return frcp(1.0f + fexp2(-1.44269504f * x)); }
__device__ __forceinline__ float tanhf_fast(float x) {
    float ax = fabsf(x);
    float e = fexp2(2.88539008f * ax);           // exp(2|x|)
    float t = 1.0f - 2.0f * frcp(e + 1.0f);      // tanh(|x|)
    return copysignf(t, x);
}

// Kernel 1: feats (B,T,6) into ws, conv skip path into d_out.
__global__ __launch_bounds__(256) void k_prep(
        const float* __restrict__ x, const float* __restrict__ Wc1,
        const float* __restrict__ Wc2, float* __restrict__ feats,
        float* __restrict__ out) {
    int idx = blockIdx.x * 256 + threadIdx.x;   // b*T + t
    if (idx >= BB * TT) return;
    int b = idx >> 12;
    int t = idx & (TT - 1);
    const float* xb = x + (size_t)b * TT * 2;
    float i0 = xb[t * 2 + 0], q0 = xb[t * 2 + 1];
    float ip = (t > 0) ? xb[(t - 1) * 2 + 0] : 0.0f;
    float qp = (t > 0) ? xb[(t - 1) * 2 + 1] : 0.0f;
    float amp2 = i0 * i0 + q0 * q0;
    float amp  = sqrtf(fmaxf(amp2, 1e-12f));
    float amp3 = amp * amp2;
    float* f = feats + (size_t)idx * 6;
    f[0] = i0; f[1] = q0; f[2] = amp; f[3] = amp3; f[4] = ip; f[5] = qp;

    float c1[3];
#pragma unroll
    for (int m = 0; m < 3; m++) {
        float acc = 0.0f;
#pragma unroll
        for (int k = 0; k < 3; k++) {
            int tt = t + (k - 1) * 16;
            if (tt >= 0 && tt < TT) {
                acc += Wc1[m * 6 + 0 * 3 + k] * xb[tt * 2 + 0];
                acc += Wc1[m * 6 + 1 * 3 + k] * xb[tt * 2 + 1];
            }
        }
        c1[m] = hswish(acc);
    }
#pragma unroll
    for (int o = 0; o < 2; o++) {
        float acc = Wc2[o * 3 + 0] * c1[0] + Wc2[o * 3 + 1] * c1[1] + Wc2[o * 3 + 2] * c1[2];
        out[(size_t)idx * 2 + o] = hswish(acc);
    }
}

// Kernel 2: delta-GRU, one block (1 CU) per batch, 512 threads (8 waves).
// K-split: lanes (l, l+32) of wave w both own row w*32+(l&31) of all 3 gates,
// each holding HALF of K=256 as packed fp16 in THREE iv64 ext-vectors
// (3 x 64 VGPRs — SSA values, cannot be demoted to scratch). Partials combine
// via shfl_xor(32); recurrent state redundantly maintained in both halves.
// amdgpu_waves_per_eu(2,2) pins the allocator at the 256-VGPR budget.
__global__ __attribute__((amdgpu_flat_work_group_size(512, 512), amdgpu_waves_per_eu(2, 2)))
void k_gru(
        const float* __restrict__ feats, const float* __restrict__ Wx,
        const float* __restrict__ Wh, const float* __restrict__ Wo,
        float* __restrict__ out) {
    __shared__ float s_out[TT * 2];                    // 32 KB output accumulator
    __shared__ __align__(16) _Float16 s_dhh[2][HH];    // 1 KB, double-buffered dh (fp16)
    __shared__ __align__(16) float s_dx[2][8];         // dx (fp32), padded to 8
    __shared__ float s_feat[2][128 * FIN];             // 6 KB, double-buffered feat windows

    const int tid  = threadIdx.x;
    const int wv   = tid >> 6;          // wave 0..7
    const int lane = tid & 63;
    const int half = lane >> 5;         // K-half 0/1
    const int row  = wv * 32 + (lane & 31);   // 0..255
    const int b    = blockIdx.x;
    const float* fb = feats + (size_t)b * TT * FIN;

    for (int i = tid; i < TT * 2; i += 512) s_out[i] = 0.0f;
    for (int i = tid; i < 128 * FIN; i += 512) s_feat[0][i] = fb[i];

    // persistent weights: 3 gate-rows, this thread's K-half, packed fp16 in iv64
    iv64 wrv{}, wzv{}, wnv{};
    {
        const int k0 = half * 128;
        const float4* p0 = (const float4*)(Wh + (size_t)(0 * HH + row) * HH + k0);
        const float4* p1 = (const float4*)(Wh + (size_t)(1 * HH + row) * HH + k0);
        const float4* p2 = (const float4*)(Wh + (size_t)(2 * HH + row) * HH + k0);
#pragma unroll
        for (int c = 0; c < 32; c++) {
            float4 v0 = p0[c], v1 = p1[c], v2 = p2[c];
            wrv[2 * c]     = packh2(v0.x, v0.y);
            wrv[2 * c + 1] = packh2(v0.z, v0.w);
            wzv[2 * c]     = packh2(v1.x, v1.y);
            wzv[2 * c + 1] = packh2(v1.z, v1.w);
            wnv[2 * c]     = packh2(v2.x, v2.y);
            wnv[2 * c + 1] = packh2(v2.z, v2.w);
        }
    }
    float wxr[FIN], wxz[FIN], wxn[FIN];
#pragma unroll
    for (int f = 0; f < FIN; f++) {
        wxr[f] = Wx[(size_t)(0 * HH + row) * FIN + f];
        wxz[f] = Wx[(size_t)(1 * HH + row) * FIN + f];
        wxn[f] = Wx[(size_t)(2 * HH + row) * FIN + f];
    }
    const float woc = Wo[half * HH + row];   // half 0 -> ch0 weights, half 1 -> ch1

    float h = 0.0f, hp = 0.0f, dmr = 0.0f, dmz = 0.0f, dmn = 0.0f, dmnh = 0.0f;
    float xp = 0.0f, curf = 0.0f;
    if (tid < FIN) curf = fb[tid];

    __syncthreads();

#pragma unroll 1
    for (int t = 0; t < TT; t++) {
        const int tb = t & 1;

        // stage NEXT feats window mid-way through the current one (WAR-safe)
        if ((t & 127) == 64 && t + 64 < TT) {
            const int w = (t >> 7) + 1;
#pragma unroll 1
            for (int i = tid; i < 128 * FIN; i += 512)
                s_feat[w & 1][i] = fb[(size_t)w * 128 * FIN + i];
        }

        // ---- phase A: thresholded deltas (redundant in both halves) ----
        {
            float dh = h - hp;
            bool keep = fabsf(dh) >= TH;
            if (half == 0) s_dhh[tb][row] = (_Float16)(keep ? dh : 0.0f);
            if (keep) hp = h;
        }
        if (tid < FIN) {
            float dx = curf - xp;
            bool keep = fabsf(dx) >= TH;
            s_dx[tb][tid] = keep ? dx : 0.0f;
            if (keep) xp = curf;
        }
        __syncthreads();

        // ---- phase B: mac_x (fp32) + half-K fp16 dot over broadcast dh ----
        float mxr = dmr, mxz = dmz, mxn = dmn;
        {
            const float4* dx4 = (const float4*)s_dx[tb];
            float4 da = dx4[0], db = dx4[1];
            mxr = fmaf(da.x, wxr[0], mxr); mxz = fmaf(da.x, wxz[0], mxz); mxn = fmaf(da.x, wxn[0], mxn);
            mxr = fmaf(da.y, wxr[1], mxr); mxz = fmaf(da.y, wxz[1], mxz); mxn = fmaf(da.y, wxn[1], mxn);
            mxr = fmaf(da.z, wxr[2], mxr); mxz = fmaf(da.z, wxz[2], mxz); mxn = fmaf(da.z, wxn[2], mxn);
            mxr = fmaf(da.w, wxr[3], mxr); mxz = fmaf(da.w, wxz[3], mxz); mxn = fmaf(da.w, wxn[3], mxn);
            mxr = fmaf(db.x, wxr[4], mxr); mxz = fmaf(db.x, wxz[4], mxz); mxn = fmaf(db.x, wxn[4], mxn);
            mxr = fmaf(db.y, wxr[5], mxr); mxz = fmaf(db.y, wxz[5], mxz); mxn = fmaf(db.y, wxn[5], mxn);
        }
        float ar = 0.0f, az = 0.0f, an = 0.0f;
        {
            const H8* dp = (const H8*)s_dhh[tb] + half * 16;
#pragma unroll
            for (int c = 0; c < 16; c++) {
                H8 d = dp[c];
                ar = __builtin_amdgcn_fdot2(d.a, toh2(wrv[4 * c + 0]), ar, false);
                az = __builtin_amdgcn_fdot2(d.a, toh2(wzv[4 * c + 0]), az, false);
                an = __builtin_amdgcn_fdot2(d.a, toh2(wnv[4 * c + 0]), an, false);
                ar = __builtin_amdgcn_fdot2(d.b, toh2(wrv[4 * c + 1]), ar, false);
                az = __builtin_amdgcn_fdot2(d.b, toh2(wzv[4 * c + 1]), az, false);
                an = __builtin_amdgcn_fdot2(d.b, toh2(wnv[4 * c + 1]), an, false);
                ar = __builtin_amdgcn_fdot2(d.c, toh2(wrv[4 * c + 2]), ar, false);
                az = __builtin_amdgcn_fdot2(d.c, toh2(wzv[4 * c + 2]), az, false);
                an = __builtin_amdgcn_fdot2(d.c, toh2(wnv[4 * c + 2]), an, false);
                ar = __builtin_amdgcn_fdot2(d.d, toh2(wrv[4 * c + 3]), ar, false);
                az = __builtin_amdgcn_fdot2(d.d, toh2(wzv[4 * c + 3]), az, false);
                an = __builtin_amdgcn_fdot2(d.d, toh2(wnv[4 * c + 3]), an, false);
            }
        }
        // combine K-halves (both sides end with identical full sums)
        ar += __shfl_xor(ar, 32, 64);
        az += __shfl_xor(az, 32, 64);
        an += __shfl_xor(an, 32, 64);

        dmr = mxr + ar;
        dmz = mxz + az;
        dmn = mxn;
        dmnh += an;

        // ---- phase C (thread-local, redundant in both halves) ----
        {
            float r = sigm(dmr);
            float z = sigm(dmz);
            float nn = tanhf_fast(dmn + r * dmnh);
            h = (1.0f - z) * nn + z * h;
        }

        // ---- output: half 0 -> channel 0, half 1 -> channel 1 ----
        {
            float p = h * woc;
            p += __shfl_xor(p, 16, 64);
            p += __shfl_xor(p, 8, 64);
            p += __shfl_xor(p, 4, 64);
            p += __shfl_xor(p, 2, 64);
            p += __shfl_xor(p, 1, 64);
            if ((lane & 31) == 0) atomicAdd(&s_out[2 * t + half], p);
        }

        // prefetch next step's feature from LDS window
        if (tid < FIN && t + 1 < TT) {
            const int tn = t + 1;
            curf = s_feat[(tn >> 7) & 1][(tn & 127) * FIN + tid];
        }
    }

    __syncthreads();
    const size_t outbase = (size_t)b * TT * 2;
    for (int i = tid; i < TT * 2; i += 512) out[outbase + i] += s_out[i];
}

extern "C" void kernel_launch(void* const* d_in, const int* in_sizes, int n_in,
                              void* d_out, int out_size, void* d_ws, size_t ws_size,
                              hipStream_t stream) {
    const float* x   = (const float*)d_in[0];
    const float* Wx  = (const float*)d_in[1];
    const float* Wh  = (const float*)d_in[2];
    const float* Wo  = (const float*)d_in[3];
    const float* Wc1 = (const float*)d_in[4];
    const float* Wc2 = (const float*)d_in[5];
    float* out = (float*)d_out;
    float* feats = (float*)d_ws;              // B*T*6 fp32 = 3.1 MB

    k_prep<<<(BB * TT + 255) / 256, 256, 0, stream>>>(x, Wc1, Wc2, feats, out);
    k_gru<<<BB, 512, 0, stream>>>(feats, Wx, Wh, Wo, out);
}